// Round 5
// baseline (286.510 us; speedup 1.0000x reference)
//
#include <hip/hip_runtime.h>

// QuaternionLinear as one 4096^3 bf16 GEMM (B^T layout).
// Round 10 (resubmit; R4 bench was an infra timeout, kernel never ran).
// R9 showed MFMA (2483 cyc/tile/CU) and LDS-read drain (2304 cyc/tile/CU)
// running SERIALLY (tile = 4913 cyc): the 12-read tile-start block (8 B
// frags + A p0) is exposed between barriers with no MFMA to hide under.
// Fix: ZERO exposed tile-start reads — every cross-tile frag is pre-read
// under the PREVIOUS tile's MFMA shadow:
//   - A x/y ping-pong extends across the tile boundary (p3 reads next p0).
//   - B ks0 half pre-read at p2 into the other parity bank; B ks1 half
//     read at p0 under the ks0 MFMA half (lgkmcnt(4) split). ks1 bank (s)
//     shared across parity (+16 VGPR total).
//   - Mid-tile vmcnt(0)+BARRIER after p1 publishes A(t+1)/B(t+1) (issued
//     >=1300 cyc earlier -> already landed; cheap) so p2/p3 can pre-read
//     from buf b^1. B(t+2) issued AFTER the wait -> no wait ever blocks a
//     fresh load; loads get >=1.5 tiles of flight.
// Sync per tile: 2 barriers (mid, end), waits vmcnt(0) mid only.
// WAR ledger:
//   A(t+1)->As[b^1] @p0: readers (tile t-1 x/y/xnext reads) lgkm-drained
//     before t-1's end BARRIER. OK
//   B(t+2)->Bs[b] @mid: readers of Bs[b] = ks0 pre-read (t-1 p2, drained
//     before t-1 end BARRIER) + ks1 read (t p0, drained by p0 LGKM0,
//     published by THIS mid BARRIER which precedes the issue). OK
//   Reads from As[b^1]/Bs[b^1] @p2/p3: published by mid BARRIER (each
//     wave vmcnt(0)-drained its own DMA stripes before it). OK
// Main loop t=0..61 unconditional; t=62 = no B-issue; t=63 peeled
// (reads/MFMA only, no sync). lgkm counted waits rely on DS in-order
// completion (HK/m218 pattern). Swizzle & addressing identical to R8/R9
// (verified 0 bank conflicts). sched_barrier(0) after every asm wait that
// gates MFMA (rule #18).

typedef __bf16 bf16x8 __attribute__((ext_vector_type(8)));
typedef float floatx4 __attribute__((ext_vector_type(4)));

constexpr int M = 4096;   // batch
constexpr int N = 4096;   // out_f * 4
constexpr int K = 4096;   // in_f * 4
constexpr int BM = 256, BN = 256, BK = 64;
constexpr int TILES = K / BK;   // 64

constexpr int CVT_BLOCKS = (M * K / 8) / 256;        // 8192: x fp32 -> bf16
constexpr int EXP_BLOCKS = (1024 * 1024 / 2) / 256;  // 2048: w -> signed Wbig

#define BARRIER() asm volatile("s_barrier" ::: "memory")
#define SB()      __builtin_amdgcn_sched_barrier(0)
#define LGKM0()   do { asm volatile("s_waitcnt lgkmcnt(0)"); SB(); } while (0)
#define LGKM4()   do { asm volatile("s_waitcnt lgkmcnt(4)"); SB(); } while (0)
#define LDS_OFF(p) ((unsigned)(uintptr_t)(__attribute__((address_space(3))) const void*)(p))

// ---------- fused prep: x -> A (bf16), w -> Wbig (sign-expanded bf16) ----------
__global__ void prep_kernel(const float* __restrict__ x, const float* __restrict__ w,
                            __bf16* __restrict__ A, __bf16* __restrict__ Wb) {
    const int b = blockIdx.x;
    if (b < CVT_BLOCKS) {
        const size_t i = (size_t)b * 256 + threadIdx.x;   // 8 elems/thread
        const float4* xp = (const float4*)x;
        float4 a = xp[2 * i];
        float4 c = xp[2 * i + 1];
        bf16x8 v;
        v[0] = (__bf16)a.x; v[1] = (__bf16)a.y; v[2] = (__bf16)a.z; v[3] = (__bf16)a.w;
        v[4] = (__bf16)c.x; v[5] = (__bf16)c.y; v[6] = (__bf16)c.z; v[7] = (__bf16)c.w;
        *(bf16x8*)(A + 8 * i) = v;
    } else {
        const int idx = (b - CVT_BLOCKS) * 256 + threadIdx.x;  // quaternion PAIR index
        const int o  = idx >> 9;
        const int ip = (idx & 511) * 2;
        float4 q0 = ((const float4*)w)[o * 1024 + ip];
        float4 q1 = ((const float4*)w)[o * 1024 + ip + 1];
        __bf16* base = Wb + (size_t)(o * 4) * K + ip * 4;
        bf16x8 r;
        r[0] = (__bf16)q0.x; r[1] = (__bf16)(-q0.y); r[2] = (__bf16)(-q0.z); r[3] = (__bf16)(-q0.w);
        r[4] = (__bf16)q1.x; r[5] = (__bf16)(-q1.y); r[6] = (__bf16)(-q1.z); r[7] = (__bf16)(-q1.w);
        *(bf16x8*)(base) = r;
        r[0] = (__bf16)q0.y; r[1] = (__bf16)q0.x; r[2] = (__bf16)q0.w; r[3] = (__bf16)(-q0.z);
        r[4] = (__bf16)q1.y; r[5] = (__bf16)q1.x; r[6] = (__bf16)q1.w; r[7] = (__bf16)(-q1.z);
        *(bf16x8*)(base + (size_t)K) = r;
        r[0] = (__bf16)q0.z; r[1] = (__bf16)(-q0.w); r[2] = (__bf16)q0.x; r[3] = (__bf16)q0.y;
        r[4] = (__bf16)q1.z; r[5] = (__bf16)(-q1.w); r[6] = (__bf16)q1.x; r[7] = (__bf16)q1.y;
        *(bf16x8*)(base + (size_t)2 * K) = r;
        r[0] = (__bf16)q0.w; r[1] = (__bf16)q0.z; r[2] = (__bf16)(-q0.y); r[3] = (__bf16)q0.x;
        r[4] = (__bf16)q1.w; r[5] = (__bf16)q1.z; r[6] = (__bf16)(-q1.y); r[7] = (__bf16)q1.x;
        *(bf16x8*)(base + (size_t)3 * K) = r;
    }
}

// ---------- async global->LDS, 16B per lane ----------
__device__ __forceinline__ void gload_lds16(const __bf16* g, __bf16* l) {
    __builtin_amdgcn_global_load_lds(
        (const __attribute__((address_space(1))) void*)g,
        (__attribute__((address_space(3))) void*)l, 16, 0, 0);
}

// ---------- manual ds_read_b128 (invisible to SIInsertWaitcnts) ----------
__device__ __forceinline__ bf16x8 dsr128(unsigned addr) {
    bf16x8 r;
    asm volatile("ds_read_b128 %0, %1" : "=v"(r) : "v"(addr));
    return r;
}

// ---------- GEMM: C[M][N] = A[M][K] * B[N][K]^T + bias[N] ----------
__global__ __launch_bounds__(512, 2) void qgemm_kernel(const __bf16* __restrict__ A,
                                                       const __bf16* __restrict__ B,
                                                       const float* __restrict__ bias,
                                                       float* __restrict__ C) {
    __shared__ __bf16 As[2][BM][BK];   // 2 x 32 KiB
    __shared__ __bf16 Bs[2][BN][BK];   // 2 x 32 KiB  (128 KiB -> 1 block/CU)

    const int tid  = threadIdx.x;
    const int wave = tid >> 6;          // 0..7
    const int lane = tid & 63;

    // Bijective XCD remap: 16x16 tile grid; each XCD owns an 8Mx4N region.
    const int bid = blockIdx.x;
    const int xcd = bid & 7;
    const int q   = bid >> 3;                       // 0..31
    const int tm  = (xcd >> 2) * 8 + (q & 7);       // 0..15
    const int tn  = (xcd & 3) * 4 + (q >> 3);       // 0..15
    const int bm  = tm * BM;
    const int bn  = tn * BN;

    const int wm = (wave >> 2) * 128;   // wave_m in {0,1} -> 128-row half
    const int wn = (wave & 3) * 64;     // wave_n in 0..3  -> 64-col slice

    // ---- staging addressing (per wave: 16-row stripe per half, 2 issues) ----
    const int srow = wave * 16 + (lane >> 3);              // 0..127 within half
    const int schk = ((lane & 7) ^ (lane >> 3)) * 8;       // pre-swizzled source
    const __bf16* agA = A + (size_t)(bm + srow) * K + schk;
    const __bf16* agB = B + (size_t)(bn + srow) * K + schk;

    auto issueA = [&](int buf, int h, int t) {
        const __bf16* g = agA + (size_t)h * 128 * K + t * BK;
        gload_lds16(g,                 &As[buf][h * 128 + wave * 16][0]);
        gload_lds16(g + (size_t)8 * K, &As[buf][h * 128 + wave * 16 + 8][0]);
    };
    auto issueB = [&](int buf, int h, int t) {
        const __bf16* g = agB + (size_t)h * 128 * K + t * BK;
        gload_lds16(g,                 &Bs[buf][h * 128 + wave * 16][0]);
        gload_lds16(g + (size_t)8 * K, &Bs[buf][h * 128 + wave * 16 + 8][0]);
    };

    // ---- fragment read addressing (32-bit LDS byte offsets) ----
    const int fl  = lane & 15;          // row-in-frag (A: m row, B: n col)
    const int fq  = lane >> 4;          // logical 16B chunk within k-slice
    const int fx7 = fl & 7;
    const unsigned ebo0 = (unsigned)(((fq)     ^ fx7) * 16);  // ks=0 byte offset
    const unsigned ebo1 = (unsigned)(((4 + fq) ^ fx7) * 16);  // ks=1 byte offset
    // row stride 128 B; frag-row stride 2048 B; buffer stride 32768 B
    const unsigned aRow = LDS_OFF(&As[0][0][0]) + (unsigned)(wm + fl) * 128u;
    const unsigned bRow = LDS_OFF(&Bs[0][0][0]) + (unsigned)(wn + fl) * 128u;

    floatx4 acc[8][4] = {};
    // A frag ping-pong sets (cycle across tiles), B ks0 parity banks, shared ks1
    bf16x8 x0, x1, x2, x3, y0, y1, y2, y3;
    bf16x8 bE0, bE1, bE2, bE3, bO0, bO1, bO2, bO3;
    bf16x8 s0, s1, s2, s3;

    // 8 MFMAs: acc rows i0,i1 x 4 n-frags, one k-slice
#define HALF(i0, i1, AA, AB, F0, F1, F2, F3)                                      \
    acc[i0][0] = __builtin_amdgcn_mfma_f32_16x16x32_bf16(AA, F0, acc[i0][0], 0, 0, 0); \
    acc[i1][0] = __builtin_amdgcn_mfma_f32_16x16x32_bf16(AB, F0, acc[i1][0], 0, 0, 0); \
    acc[i0][1] = __builtin_amdgcn_mfma_f32_16x16x32_bf16(AA, F1, acc[i0][1], 0, 0, 0); \
    acc[i1][1] = __builtin_amdgcn_mfma_f32_16x16x32_bf16(AB, F1, acc[i1][1], 0, 0, 0); \
    acc[i0][2] = __builtin_amdgcn_mfma_f32_16x16x32_bf16(AA, F2, acc[i0][2], 0, 0, 0); \
    acc[i1][2] = __builtin_amdgcn_mfma_f32_16x16x32_bf16(AB, F2, acc[i1][2], 0, 0, 0); \
    acc[i0][3] = __builtin_amdgcn_mfma_f32_16x16x32_bf16(AA, F3, acc[i0][3], 0, 0, 0); \
    acc[i1][3] = __builtin_amdgcn_mfma_f32_16x16x32_bf16(AB, F3, acc[i1][3], 0, 0, 0)

    // One K-tile. BUFC = literal 0/1. BC* = current ks0 bank, BX* = next ks0
    // bank (pre-read at p2). ISSB = issue B(t+2).
#define TILE(T, BUFC, BC0, BC1, BC2, BC3, BX0, BX1, BX2, BX3, ISSB)               \
    do {                                                                          \
        const unsigned bsc_ = (BUFC) * 32768u;                                    \
        const unsigned bsn_ = (1 - (BUFC)) * 32768u;                              \
        /* p0: issue A(t+1); read cur ks1 (s) + A p1 (y); MFMA rows 0,1 */        \
        issueA(1 - (BUFC), 0, (T) + 1); issueA(1 - (BUFC), 1, (T) + 1);           \
        s0 = dsr128(bRow + bsc_ + 0u    + ebo1);                                  \
        s1 = dsr128(bRow + bsc_ + 2048u + ebo1);                                  \
        s2 = dsr128(bRow + bsc_ + 4096u + ebo1);                                  \
        s3 = dsr128(bRow + bsc_ + 6144u + ebo1);                                  \
        y0 = dsr128(aRow + bsc_ + 4096u + ebo0);                                  \
        y1 = dsr128(aRow + bsc_ + 4096u + ebo1);                                  \
        y2 = dsr128(aRow + bsc_ + 6144u + ebo0);                                  \
        y3 = dsr128(aRow + bsc_ + 6144u + ebo1);                                  \
        SB();                                                                     \
        __builtin_amdgcn_s_setprio(1);                                            \
        HALF(0, 1, x0, x2, BC0, BC1, BC2, BC3);                                   \
        __builtin_amdgcn_s_setprio(0);                                            \
        LGKM4();  /* s drained; y outstanding */                                  \
        __builtin_amdgcn_s_setprio(1);                                            \
        HALF(0, 1, x1, x3, s0, s1, s2, s3);                                       \
        __builtin_amdgcn_s_setprio(0);                                            \
        LGKM0();                                                                  \
        /* p1: read A p2 (x); MFMA rows 2,3; then mid sync + B(t+2) issue */      \
        x0 = dsr128(aRow + bsc_ + 8192u  + ebo0);                                 \
        x1 = dsr128(aRow + bsc_ + 8192u  + ebo1);                                 \
        x2 = dsr128(aRow + bsc_ + 10240u + ebo0);                                 \
        x3 = dsr128(aRow + bsc_ + 10240u + ebo1);                                 \
        SB();                                                                     \
        __builtin_amdgcn_s_setprio(1);                                            \
        HALF(2, 3, y0, y2, BC0, BC1, BC2, BC3);                                   \
        HALF(2, 3, y1, y3, s0, s1, s2, s3);                                       \
        __builtin_amdgcn_s_setprio(0);                                            \
        LGKM0();                                                                  \
        asm volatile("s_waitcnt vmcnt(0)");  /* A(t+1),B(t+1) landed (old) */     \
        BARRIER();                           /* publish cross-wave */             \
        if (ISSB) { issueB((BUFC), 0, (T) + 2); issueB((BUFC), 1, (T) + 2); }     \
        /* p2: read A p3 (y) + NEXT ks0 (BX from buf^1); MFMA rows 4,5 */         \
        y0 = dsr128(aRow + bsc_ + 12288u + ebo0);                                 \
        y1 = dsr128(aRow + bsc_ + 12288u + ebo1);                                 \
        y2 = dsr128(aRow + bsc_ + 14336u + ebo0);                                 \
        y3 = dsr128(aRow + bsc_ + 14336u + ebo1);                                 \
        BX0 = dsr128(bRow + bsn_ + 0u    + ebo0);                                 \
        BX1 = dsr128(bRow + bsn_ + 2048u + ebo0);                                 \
        BX2 = dsr128(bRow + bsn_ + 4096u + ebo0);                                 \
        BX3 = dsr128(bRow + bsn_ + 6144u + ebo0);                                 \
        SB();                                                                     \
        __builtin_amdgcn_s_setprio(1);                                            \
        HALF(4, 5, x0, x2, BC0, BC1, BC2, BC3);                                   \
        HALF(4, 5, x1, x3, s0, s1, s2, s3);                                       \
        __builtin_amdgcn_s_setprio(0);                                            \
        LGKM4();  /* y drained; BX outstanding */                                 \
        /* p3: read NEXT A p0 (x from buf^1); MFMA rows 6,7 */                    \
        x0 = dsr128(aRow + bsn_ + 0u    + ebo0);                                  \
        x1 = dsr128(aRow + bsn_ + 0u    + ebo1);                                  \
        x2 = dsr128(aRow + bsn_ + 2048u + ebo0);                                  \
        x3 = dsr128(aRow + bsn_ + 2048u + ebo1);                                  \
        SB();                                                                     \
        __builtin_amdgcn_s_setprio(1);                                            \
        HALF(6, 7, y0, y2, BC0, BC1, BC2, BC3);                                   \
        HALF(6, 7, y1, y3, s0, s1, s2, s3);                                       \
        __builtin_amdgcn_s_setprio(0);                                            \
        LGKM0();  /* BX + next-x drained */                                       \
        BARRIER();                           /* WAR publish for next p0 DMA */    \
    } while (0)

    // ---- prologue: issue B(0), A(0), B(1); pre-read tile0 frags ----
    issueB(0, 0, 0); issueB(0, 1, 0);
    issueA(0, 0, 0); issueA(0, 1, 0);
    issueB(1, 0, 1); issueB(1, 1, 1);
    asm volatile("s_waitcnt vmcnt(4)");  // B(0),A(0) landed; B(1) in flight
    BARRIER();
    bE0 = dsr128(bRow + 0u    + ebo0);
    bE1 = dsr128(bRow + 2048u + ebo0);
    bE2 = dsr128(bRow + 4096u + ebo0);
    bE3 = dsr128(bRow + 6144u + ebo0);
    x0  = dsr128(aRow + 0u    + ebo0);
    x1  = dsr128(aRow + 0u    + ebo1);
    x2  = dsr128(aRow + 2048u + ebo0);
    x3  = dsr128(aRow + 2048u + ebo1);
    LGKM0();

    for (int t = 0; t < 62; t += 2) {
        TILE(t,     0, bE0, bE1, bE2, bE3, bO0, bO1, bO2, bO3, true);
        TILE(t + 1, 1, bO0, bO1, bO2, bO3, bE0, bE1, bE2, bE3, true);
    }
    TILE(62, 0, bE0, bE1, bE2, bE3, bO0, bO1, bO2, bO3, false);

    // ---- peeled tile 63 (buf 1): reads + MFMA only, no sync needed ----
    {
        const unsigned bsc_ = 32768u;
        s0 = dsr128(bRow + bsc_ + 0u    + ebo1);
        s1 = dsr128(bRow + bsc_ + 2048u + ebo1);
        s2 = dsr128(bRow + bsc_ + 4096u + ebo1);
        s3 = dsr128(bRow + bsc_ + 6144u + ebo1);
        y0 = dsr128(aRow + bsc_ + 4096u + ebo0);
        y1 = dsr128(aRow + bsc_ + 4096u + ebo1);
        y2 = dsr128(aRow + bsc_ + 6144u + ebo0);
        y3 = dsr128(aRow + bsc_ + 6144u + ebo1);
        SB();
        __builtin_amdgcn_s_setprio(1);
        HALF(0, 1, x0, x2, bO0, bO1, bO2, bO3);
        __builtin_amdgcn_s_setprio(0);
        LGKM4();
        __builtin_amdgcn_s_setprio(1);
        HALF(0, 1, x1, x3, s0, s1, s2, s3);
        __builtin_amdgcn_s_setprio(0);
        LGKM0();
        x0 = dsr128(aRow + bsc_ + 8192u  + ebo0);
        x1 = dsr128(aRow + bsc_ + 8192u  + ebo1);
        x2 = dsr128(aRow + bsc_ + 10240u + ebo0);
        x3 = dsr128(aRow + bsc_ + 10240u + ebo1);
        SB();
        __builtin_amdgcn_s_setprio(1);
        HALF(2, 3, y0, y2, bO0, bO1, bO2, bO3);
        HALF(2, 3, y1, y3, s0, s1, s2, s3);
        __builtin_amdgcn_s_setprio(0);
        LGKM0();
        y0 = dsr128(aRow + bsc_ + 12288u + ebo0);
        y1 = dsr128(aRow + bsc_ + 12288u + ebo1);
        y2 = dsr128(aRow + bsc_ + 14336u + ebo0);
        y3 = dsr128(aRow + bsc_ + 14336u + ebo1);
        SB();
        __builtin_amdgcn_s_setprio(1);
        HALF(4, 5, x0, x2, bO0, bO1, bO2, bO3);
        HALF(4, 5, x1, x3, s0, s1, s2, s3);
        __builtin_amdgcn_s_setprio(0);
        LGKM0();
        __builtin_amdgcn_s_setprio(1);
        HALF(6, 7, y0, y2, bO0, bO1, bO2, bO3);
        HALF(6, 7, y1, y3, s0, s1, s2, s3);
        __builtin_amdgcn_s_setprio(0);
    }

    // epilogue: C/D layout col = lane&15, row = (lane>>4)*4 + reg (verified R1)
#pragma unroll
    for (int mt = 0; mt < 8; ++mt) {
        const int row = bm + wm + mt * 16 + fq * 4;
#pragma unroll
        for (int nt = 0; nt < 4; ++nt) {
            const int col = bn + wn + nt * 16 + fl;
            const float bv = bias[col];
            float* cp = C + (size_t)row * N + col;
#pragma unroll
            for (int r = 0; r < 4; ++r)
                cp[(size_t)r * N] = acc[mt][nt][r] + bv;
        }
    }
#undef TILE
#undef HALF
}

extern "C" void kernel_launch(void* const* d_in, const int* in_sizes, int n_in,
                              void* d_out, int out_size, void* d_ws, size_t ws_size,
                              hipStream_t stream) {
    const float* x    = (const float*)d_in[0];   // (4096,1024,4) fp32
    const float* w    = (const float*)d_in[1];   // (1024,1024,4) fp32
    const float* bias = (const float*)d_in[2];   // (1024,4) fp32
    float* out = (float*)d_out;                  // (4096,1024,4) fp32

    __bf16* Abf  = (__bf16*)d_ws;                                   // 32 MB
    __bf16* Wbig = (__bf16*)((char*)d_ws + (size_t)M * K * 2);      // 32 MB

    prep_kernel<<<CVT_BLOCKS + EXP_BLOCKS, 256, 0, stream>>>(x, w, Abf, Wbig);

    qgemm_kernel<<<256, 512, 0, stream>>>(Abf, Wbig, bias, out);
}

// Round 6
// 235.899 us; speedup vs baseline: 1.2145x; 1.2145x over previous
//
#include <hip/hip_runtime.h>

// QuaternionLinear as one 4096^3 bf16 GEMM (B^T layout).
// Round 11: R10 failed because its mid-tile vmcnt(0) waited on A(t+1)
// issued only ~2 phases earlier (fresh load + LDS-write contention ->
// exposed latency every tile). Fix: TRIPLE-buffered A (As[3], 96 KiB) +
// double B (64 KiB) = 160 KiB LDS. A(t+2) issues at tile t p0 (1.5-tile
// flight); B(t+2) after tile t mid (1-tile flight). Mid-tile publish is
// counted vmcnt(4) (only A(t+2) newer) -> no fresh-load wait anywhere
// (vmcnt(0) only at t=62). Zero exposed read bursts: every phase's 4-8
// ds_reads issue right before a 16-MFMA cluster and drain under it via
// counted lgkmcnt; next-tile x (A p0) and bC (B ks0) pre-read at p3/p2.
// Per tile: 2 barriers (mid, end), 1 counted vmcnt, 4 counted lgkm.
// WAR ledger (steady tile t, a=t%3, b=t&1):
//   A(t+2)->As[(t+2)%3] @p0: prior readers = tile t-1 (its main buffer),
//     drained by t-1 p3 waits, published BAR(end,t-1). OK
//   B(t+2)->Bs[b] @after-mid: readers of B(t) = bC pre-read (t-1 p2,
//     published BAR(end,t-1)) + s read (t p0, drained p0 LGKM4,
//     published BAR(mid,t) which precedes the issue). OK
//   xN read As[(t+1)%3] @p3 / bX read Bs[b^1] @p2: A(t+1) issued t-1 p0,
//     B(t+1) issued t-1 mid; both drained by vmcnt(4) @t mid, published
//     BAR(mid,t). Next writer of As[(t+1)%3] is A(t+4) @t+2 p0, after
//     BAR(end,t+1) which published all its readers. OK
// ds_read offsets are 16-bit immediates off 10 base regs (3 A-bufs x
// 2 swizzle-parities + 2 B-bufs x 2). Swizzle identical to R8-R10
// (verified 0 bank conflicts). sched_barrier(0) after every wait that
// gates MFMA (rule #18).

typedef __bf16 bf16x8 __attribute__((ext_vector_type(8)));
typedef float floatx4 __attribute__((ext_vector_type(4)));

constexpr int M = 4096;   // batch
constexpr int N = 4096;   // out_f * 4
constexpr int K = 4096;   // in_f * 4
constexpr int BM = 256, BN = 256, BK = 64;

constexpr int CVT_BLOCKS = (M * K / 8) / 256;        // 8192: x fp32 -> bf16
constexpr int EXP_BLOCKS = (1024 * 1024 / 2) / 256;  // 2048: w -> signed Wbig

#define BARRIER() asm volatile("s_barrier" ::: "memory")
#define SB()      __builtin_amdgcn_sched_barrier(0)
#define LGKM0()   do { asm volatile("s_waitcnt lgkmcnt(0)"); SB(); } while (0)
#define LGKM4()   do { asm volatile("s_waitcnt lgkmcnt(4)"); SB(); } while (0)
#define LDS_OFF(p) ((unsigned)(uintptr_t)(__attribute__((address_space(3))) const void*)(p))

// ---------- fused prep: x -> A (bf16), w -> Wbig (sign-expanded bf16) ----------
__global__ void prep_kernel(const float* __restrict__ x, const float* __restrict__ w,
                            __bf16* __restrict__ A, __bf16* __restrict__ Wb) {
    const int b = blockIdx.x;
    if (b < CVT_BLOCKS) {
        const size_t i = (size_t)b * 256 + threadIdx.x;   // 8 elems/thread
        const float4* xp = (const float4*)x;
        float4 a = xp[2 * i];
        float4 c = xp[2 * i + 1];
        bf16x8 v;
        v[0] = (__bf16)a.x; v[1] = (__bf16)a.y; v[2] = (__bf16)a.z; v[3] = (__bf16)a.w;
        v[4] = (__bf16)c.x; v[5] = (__bf16)c.y; v[6] = (__bf16)c.z; v[7] = (__bf16)c.w;
        *(bf16x8*)(A + 8 * i) = v;
    } else {
        const int idx = (b - CVT_BLOCKS) * 256 + threadIdx.x;  // quaternion PAIR index
        const int o  = idx >> 9;
        const int ip = (idx & 511) * 2;
        float4 q0 = ((const float4*)w)[o * 1024 + ip];
        float4 q1 = ((const float4*)w)[o * 1024 + ip + 1];
        __bf16* base = Wb + (size_t)(o * 4) * K + ip * 4;
        bf16x8 r;
        r[0] = (__bf16)q0.x; r[1] = (__bf16)(-q0.y); r[2] = (__bf16)(-q0.z); r[3] = (__bf16)(-q0.w);
        r[4] = (__bf16)q1.x; r[5] = (__bf16)(-q1.y); r[6] = (__bf16)(-q1.z); r[7] = (__bf16)(-q1.w);
        *(bf16x8*)(base) = r;
        r[0] = (__bf16)q0.y; r[1] = (__bf16)q0.x; r[2] = (__bf16)q0.w; r[3] = (__bf16)(-q0.z);
        r[4] = (__bf16)q1.y; r[5] = (__bf16)q1.x; r[6] = (__bf16)q1.w; r[7] = (__bf16)(-q1.z);
        *(bf16x8*)(base + (size_t)K) = r;
        r[0] = (__bf16)q0.z; r[1] = (__bf16)(-q0.w); r[2] = (__bf16)q0.x; r[3] = (__bf16)q0.y;
        r[4] = (__bf16)q1.z; r[5] = (__bf16)(-q1.w); r[6] = (__bf16)q1.x; r[7] = (__bf16)q1.y;
        *(bf16x8*)(base + (size_t)2 * K) = r;
        r[0] = (__bf16)q0.w; r[1] = (__bf16)q0.z; r[2] = (__bf16)(-q0.y); r[3] = (__bf16)q0.x;
        r[4] = (__bf16)q1.w; r[5] = (__bf16)q1.z; r[6] = (__bf16)(-q1.y); r[7] = (__bf16)q1.x;
        *(bf16x8*)(base + (size_t)3 * K) = r;
    }
}

// ---------- async global->LDS, 16B per lane ----------
__device__ __forceinline__ void gload_lds16(const __bf16* g, __bf16* l) {
    __builtin_amdgcn_global_load_lds(
        (const __attribute__((address_space(1))) void*)g,
        (__attribute__((address_space(3))) void*)l, 16, 0, 0);
}

// ---------- manual ds_read_b128 with immediate offset ----------
template <int OFF>
__device__ __forceinline__ bf16x8 dsrO(unsigned base) {
    bf16x8 r;
    asm volatile("ds_read_b128 %0, %1 offset:%c2" : "=v"(r) : "v"(base), "i"(OFF));
    return r;
}

// ---------- GEMM: C[M][N] = A[M][K] * B[N][K]^T + bias[N] ----------
__global__ __launch_bounds__(512, 2) void qgemm_kernel(const __bf16* __restrict__ A,
                                                       const __bf16* __restrict__ B,
                                                       const float* __restrict__ bias,
                                                       float* __restrict__ C) {
    __shared__ __bf16 As[3][BM][BK];   // 3 x 32 KiB (triple-buffered A)
    __shared__ __bf16 Bs[2][BN][BK];   // 2 x 32 KiB -> 160 KiB total, 1 block/CU

    const int tid  = threadIdx.x;
    const int wave = tid >> 6;          // 0..7
    const int lane = tid & 63;

    // Bijective XCD remap: 16x16 tile grid; each XCD owns an 8Mx4N region.
    const int bid = blockIdx.x;
    const int xcd = bid & 7;
    const int q   = bid >> 3;                       // 0..31
    const int tm  = (xcd >> 2) * 8 + (q & 7);       // 0..15
    const int tn  = (xcd & 3) * 4 + (q >> 3);       // 0..15
    const int bm  = tm * BM;
    const int bn  = tn * BN;

    const int wm = (wave >> 2) * 128;   // wave_m in {0,1} -> 128-row half
    const int wn = (wave & 3) * 64;     // wave_n in 0..3  -> 64-col slice

    // ---- staging addressing (per wave: 16-row stripe per half, 2 issues) ----
    const int srow = wave * 16 + (lane >> 3);              // 0..127 within half
    const int schk = ((lane & 7) ^ (lane >> 3)) * 8;       // pre-swizzled source
    const __bf16* agA = A + (size_t)(bm + srow) * K + schk;
    const __bf16* agB = B + (size_t)(bn + srow) * K + schk;

    auto issueA = [&](int buf, int h, int t) {
        const __bf16* g = agA + (size_t)h * 128 * K + t * BK;
        gload_lds16(g,                 &As[buf][h * 128 + wave * 16][0]);
        gload_lds16(g + (size_t)8 * K, &As[buf][h * 128 + wave * 16 + 8][0]);
    };
    auto issueB = [&](int buf, int h, int t) {
        const __bf16* g = agB + (size_t)h * 128 * K + t * BK;
        gload_lds16(g,                 &Bs[buf][h * 128 + wave * 16][0]);
        gload_lds16(g + (size_t)8 * K, &Bs[buf][h * 128 + wave * 16 + 8][0]);
    };

    // ---- fragment read addressing: 10 base regs + 16-bit imm offsets ----
    const int fl  = lane & 15;          // row-in-frag (A: m row, B: n col)
    const int fq  = lane >> 4;          // logical 16B chunk within k-slice
    const int fx7 = fl & 7;
    const unsigned ebo0 = (unsigned)(((fq)     ^ fx7) * 16);  // ks=0 byte offset
    const unsigned ebo1 = (unsigned)(((4 + fq) ^ fx7) * 16);  // ks=1 byte offset
    // row stride 128 B; frag-row stride 2048 B; phase stride 4096 B; buf 32768 B
    const unsigned aR0  = LDS_OFF(&As[0][0][0]) + (unsigned)(wm + fl) * 128u + ebo0;
    const unsigned aR1  = LDS_OFF(&As[0][0][0]) + (unsigned)(wm + fl) * 128u + ebo1;
    const unsigned aR0b1 = aR0 + 32768u, aR1b1 = aR1 + 32768u;
    const unsigned aR0b2 = aR0 + 65536u, aR1b2 = aR1 + 65536u;
    const unsigned bR0  = LDS_OFF(&Bs[0][0][0]) + (unsigned)(wn + fl) * 128u + ebo0;
    const unsigned bR1  = LDS_OFF(&Bs[0][0][0]) + (unsigned)(wn + fl) * 128u + ebo1;
    const unsigned bR0b1 = bR0 + 32768u, bR1b1 = bR1 + 32768u;

    floatx4 acc[8][4] = {};
    bf16x8 x0, x1, x2, x3;      // A p0 (cur tile), pre-read prev p3
    bf16x8 y0, y1, y2, y3;      // A p1
    bf16x8 w0, w1, w2, w3;      // A p2
    bf16x8 z0, z1, z2, z3;      // A p3
    bf16x8 s0, s1, s2, s3;      // B ks1 (cur)
    bf16x8 c0, c1, c2, c3;      // B ks0 (cur), pre-read prev p2
    bf16x8 d0, d1, d2, d3;      // B ks0 (next) staging bank
    bf16x8 n0, n1, n2, n3;      // A p0 (next) staging bank

    // 8 MFMAs: acc rows i0,i1 x 4 n-frags, one k-slice
#define HALFK(i0, i1, AA, AB, F0, F1, F2, F3)                                     \
    acc[i0][0] = __builtin_amdgcn_mfma_f32_16x16x32_bf16(AA, F0, acc[i0][0], 0, 0, 0); \
    acc[i1][0] = __builtin_amdgcn_mfma_f32_16x16x32_bf16(AB, F0, acc[i1][0], 0, 0, 0); \
    acc[i0][1] = __builtin_amdgcn_mfma_f32_16x16x32_bf16(AA, F1, acc[i0][1], 0, 0, 0); \
    acc[i1][1] = __builtin_amdgcn_mfma_f32_16x16x32_bf16(AB, F1, acc[i1][1], 0, 0, 0); \
    acc[i0][2] = __builtin_amdgcn_mfma_f32_16x16x32_bf16(AA, F2, acc[i0][2], 0, 0, 0); \
    acc[i1][2] = __builtin_amdgcn_mfma_f32_16x16x32_bf16(AB, F2, acc[i1][2], 0, 0, 0); \
    acc[i0][3] = __builtin_amdgcn_mfma_f32_16x16x32_bf16(AA, F3, acc[i0][3], 0, 0, 0); \
    acc[i1][3] = __builtin_amdgcn_mfma_f32_16x16x32_bf16(AB, F3, acc[i1][3], 0, 0, 0)

    // One K-tile. A0c/A1c: cur A bases (ks0/ks1); A0n/A1n: next A buffer;
    // B0c/B1c: cur B; B0x: other-parity B ks0. DA: As dest for A(t+2);
    // DB: Bs dest for B(t+2). ISSA/ISSB literal bools; MIDVM literal 4/0.
#define TILE(T, A0c, A1c, A0n, A1n, B0c, B1c, B0x, DA, DB, ISSA, ISSB, MIDVM)     \
    do {                                                                          \
        /* p0: issue A(t+2); read s(B ks1)+y(A p1); MFMA rows 0,1 */              \
        if (ISSA) { issueA(DA, 0, (T) + 2); issueA(DA, 1, (T) + 2); }             \
        s0 = dsrO<0>(B1c); s1 = dsrO<2048>(B1c);                                  \
        s2 = dsrO<4096>(B1c); s3 = dsrO<6144>(B1c);                               \
        y0 = dsrO<4096>(A0c); y1 = dsrO<4096>(A1c);                               \
        y2 = dsrO<6144>(A0c); y3 = dsrO<6144>(A1c);                               \
        SB();                                                                     \
        __builtin_amdgcn_s_setprio(1);                                            \
        HALFK(0, 1, x0, x2, c0, c1, c2, c3);                                      \
        __builtin_amdgcn_s_setprio(0);                                            \
        LGKM4();  /* s done; y outstanding */                                     \
        __builtin_amdgcn_s_setprio(1);                                            \
        HALFK(0, 1, x1, x3, s0, s1, s2, s3);                                      \
        __builtin_amdgcn_s_setprio(0);                                            \
        /* p1: read w(A p2); MFMA rows 2,3; counted-vm mid publish */             \
        w0 = dsrO<8192>(A0c); w1 = dsrO<8192>(A1c);                               \
        w2 = dsrO<10240>(A0c); w3 = dsrO<10240>(A1c);                             \
        SB();                                                                     \
        LGKM4();  /* y done; w outstanding */                                     \
        __builtin_amdgcn_s_setprio(1);                                            \
        HALFK(2, 3, y0, y2, c0, c1, c2, c3);                                      \
        HALFK(2, 3, y1, y3, s0, s1, s2, s3);                                      \
        __builtin_amdgcn_s_setprio(0);                                            \
        LGKM0();  /* w done */                                                    \
        asm volatile("s_waitcnt vmcnt(" #MIDVM ")");  /* A(t+1),B(t+1) landed */  \
        BARRIER();                                    /* publish cross-wave */    \
        if (ISSB) { issueB(DB, 0, (T) + 2); issueB(DB, 1, (T) + 2); }             \
        /* p2: read z(A p3)+d(next B ks0); MFMA rows 4,5 (no wait needed) */      \
        z0 = dsrO<12288>(A0c); z1 = dsrO<12288>(A1c);                             \
        z2 = dsrO<14336>(A0c); z3 = dsrO<14336>(A1c);                             \
        d0 = dsrO<0>(B0x); d1 = dsrO<2048>(B0x);                                  \
        d2 = dsrO<4096>(B0x); d3 = dsrO<6144>(B0x);                               \
        SB();                                                                     \
        __builtin_amdgcn_s_setprio(1);                                            \
        HALFK(4, 5, w0, w2, c0, c1, c2, c3);                                      \
        HALFK(4, 5, w1, w3, s0, s1, s2, s3);                                      \
        __builtin_amdgcn_s_setprio(0);                                            \
        /* p3: read n(next A p0); MFMA rows 6,7 */                                \
        LGKM4();  /* z done; d outstanding */                                     \
        n0 = dsrO<0>(A0n); n1 = dsrO<0>(A1n);                                     \
        n2 = dsrO<2048>(A0n); n3 = dsrO<2048>(A1n);                               \
        SB();                                                                     \
        __builtin_amdgcn_s_setprio(1);                                            \
        HALFK(6, 7, z0, z2, c0, c1, c2, c3);                                      \
        HALFK(6, 7, z1, z3, s0, s1, s2, s3);                                      \
        __builtin_amdgcn_s_setprio(0);                                            \
        LGKM0();  /* d, n done (needed by next p0 MFMA) */                        \
        BARRIER();                                    /* WAR publish */           \
        x0 = n0; x1 = n1; x2 = n2; x3 = n3;                                       \
        c0 = d0; c1 = d1; c2 = d2; c3 = d3;                                       \
    } while (0)

    // ---- prologue: stage tiles 0,1; pre-read x (A0 p0) + c (B0 ks0) ----
    issueB(0, 0, 0); issueB(0, 1, 0);
    issueA(0, 0, 0); issueA(0, 1, 0);
    issueB(1, 0, 1); issueB(1, 1, 1);
    issueA(1, 0, 1); issueA(1, 1, 1);
    asm volatile("s_waitcnt vmcnt(0)");
    BARRIER();
    x0 = dsrO<0>(aR0);    x1 = dsrO<0>(aR1);
    x2 = dsrO<2048>(aR0); x3 = dsrO<2048>(aR1);
    c0 = dsrO<0>(bR0);    c1 = dsrO<2048>(bR0);
    c2 = dsrO<4096>(bR0); c3 = dsrO<6144>(bR0);
    LGKM0();

    for (int t = 0; t < 60; t += 6) {
        TILE(t + 0, aR0,   aR1,   aR0b1, aR1b1, bR0,   bR1,   bR0b1, 2, 0, true, true, 4);
        TILE(t + 1, aR0b1, aR1b1, aR0b2, aR1b2, bR0b1, bR1b1, bR0,   0, 1, true, true, 4);
        TILE(t + 2, aR0b2, aR1b2, aR0,   aR1,   bR0,   bR1,   bR0b1, 1, 0, true, true, 4);
        TILE(t + 3, aR0,   aR1,   aR0b1, aR1b1, bR0b1, bR1b1, bR0,   2, 1, true, true, 4);
        TILE(t + 4, aR0b1, aR1b1, aR0b2, aR1b2, bR0,   bR1,   bR0b1, 0, 0, true, true, 4);
        TILE(t + 5, aR0b2, aR1b2, aR0,   aR1,   bR0b1, bR1b1, bR0,   1, 1, true, true, 4);
    }
    TILE(60, aR0,   aR1,   aR0b1, aR1b1, bR0,   bR1,   bR0b1, 2, 0, true,  true,  4);
    TILE(61, aR0b1, aR1b1, aR0b2, aR1b2, bR0b1, bR1b1, bR0,   0, 1, true,  true,  4);
    TILE(62, aR0b2, aR1b2, aR0,   aR1,   bR0,   bR1,   bR0b1, 1, 0, false, false, 0);

    // ---- peeled tile 63 (a=0, b=1): reads + MFMA only, no sync/issues ----
    {
        s0 = dsrO<0>(bR1b1); s1 = dsrO<2048>(bR1b1);
        s2 = dsrO<4096>(bR1b1); s3 = dsrO<6144>(bR1b1);
        y0 = dsrO<4096>(aR0); y1 = dsrO<4096>(aR1);
        y2 = dsrO<6144>(aR0); y3 = dsrO<6144>(aR1);
        SB();
        __builtin_amdgcn_s_setprio(1);
        HALFK(0, 1, x0, x2, c0, c1, c2, c3);
        __builtin_amdgcn_s_setprio(0);
        LGKM4();
        __builtin_amdgcn_s_setprio(1);
        HALFK(0, 1, x1, x3, s0, s1, s2, s3);
        __builtin_amdgcn_s_setprio(0);
        w0 = dsrO<8192>(aR0); w1 = dsrO<8192>(aR1);
        w2 = dsrO<10240>(aR0); w3 = dsrO<10240>(aR1);
        SB();
        LGKM4();
        __builtin_amdgcn_s_setprio(1);
        HALFK(2, 3, y0, y2, c0, c1, c2, c3);
        HALFK(2, 3, y1, y3, s0, s1, s2, s3);
        __builtin_amdgcn_s_setprio(0);
        LGKM0();
        z0 = dsrO<12288>(aR0); z1 = dsrO<12288>(aR1);
        z2 = dsrO<14336>(aR0); z3 = dsrO<14336>(aR1);
        SB();
        __builtin_amdgcn_s_setprio(1);
        HALFK(4, 5, w0, w2, c0, c1, c2, c3);
        HALFK(4, 5, w1, w3, s0, s1, s2, s3);
        __builtin_amdgcn_s_setprio(0);
        LGKM0();
        __builtin_amdgcn_s_setprio(1);
        HALFK(6, 7, z0, z2, c0, c1, c2, c3);
        HALFK(6, 7, z1, z3, s0, s1, s2, s3);
        __builtin_amdgcn_s_setprio(0);
    }

    // epilogue: C/D layout col = lane&15, row = (lane>>4)*4 + reg (verified R1)
#pragma unroll
    for (int mt = 0; mt < 8; ++mt) {
        const int row = bm + wm + mt * 16 + fq * 4;
#pragma unroll
        for (int nt = 0; nt < 4; ++nt) {
            const int col = bn + wn + nt * 16 + fl;
            const float bv = bias[col];
            float* cp = C + (size_t)row * N + col;
#pragma unroll
            for (int r = 0; r < 4; ++r)
                cp[(size_t)r * N] = acc[mt][nt][r] + bv;
        }
    }
#undef TILE
#undef HALFK
}

extern "C" void kernel_launch(void* const* d_in, const int* in_sizes, int n_in,
                              void* d_out, int out_size, void* d_ws, size_t ws_size,
                              hipStream_t stream) {
    const float* x    = (const float*)d_in[0];   // (4096,1024,4) fp32
    const float* w    = (const float*)d_in[1];   // (1024,1024,4) fp32
    const float* bias = (const float*)d_in[2];   // (1024,4) fp32
    float* out = (float*)d_out;                  // (4096,1024,4) fp32

    __bf16* Abf  = (__bf16*)d_ws;                                   // 32 MB
    __bf16* Wbig = (__bf16*)((char*)d_ws + (size_t)M * K * 2);      // 32 MB

    prep_kernel<<<CVT_BLOCKS + EXP_BLOCKS, 256, 0, stream>>>(x, w, Abf, Wbig);

    qgemm_kernel<<<256, 512, 0, stream>>>(Abf, Wbig, bias, out);
}